// Round 19
// baseline (127.551 us; speedup 1.0000x reference)
//
#include <hip/hip_runtime.h>
#include <hip/hip_bf16.h>
#include <math.h>

#define B_ 4
#define N_ 256
#define M_ 512
#define E_ 256
#define H_ 64

typedef __attribute__((ext_vector_type(8))) short bf16x8;
typedef __attribute__((ext_vector_type(4))) float f32x4;
typedef __attribute__((ext_vector_type(2))) float f32x2;

__device__ __forceinline__ f32x2 pfma(f32x2 a, f32x2 b, f32x2 c) {
    return __builtin_elementwise_fma(a, b, c);
}

// packed-pair tanh-form gelu with raw v_exp_f32:
// gelu(x) = x * rcp(1 + exp2(-k1*x - k2*x^3)); saturates correctly, NaN-free.
__device__ __forceinline__ f32x2 gelu2(f32x2 x) {
    f32x2 t = x * x;
    f32x2 k2; k2.x = -0.10294377f; k2.y = -0.10294377f;
    f32x2 k1; k1.x = -2.3022081f;  k1.y = -2.3022081f;
    f32x2 u = pfma(t, k2, k1);
    f32x2 un = x * u;
    f32x2 E;
    E.x = __builtin_amdgcn_exp2f(un.x);
    E.y = __builtin_amdgcn_exp2f(un.y);
    f32x2 one; one.x = 1.0f; one.y = 1.0f;
    f32x2 d = E + one;
    f32x2 r; r.x = __builtin_amdgcn_rcpf(d.x); r.y = __builtin_amdgcn_rcpf(d.y);
    return x * r;
}

// exact (erf) gelu for the FiLM generator path (params kernel only)
__device__ __forceinline__ float gelu_e(float x) {
    return 0.5f * x * (1.0f + erff(x * 0.70710678118654752f));
}

// fp32 -> bf16 bits via native convert (RNE)
__device__ __forceinline__ short sbf(float f) {
    __bf16 h = (__bf16)f;
    return __builtin_bit_cast(short, h);
}

// Per-(b,n): FiLM params + per-bn distance max. 256 threads.
// par[bn*sb] = { A1[64], A0[64], T[64], S[64] }
__global__ __launch_bounds__(256) void film_params_kernel(
    const float* __restrict__ z, const float* __restrict__ mu,
    const float* __restrict__ emb,
    const float* __restrict__ fg_w1, const float* __restrict__ fg_b1,
    const float* __restrict__ fg_w2, const float* __restrict__ fg_b2,
    const float* __restrict__ kn_w0, const float* __restrict__ kn_b0,
    const float* __restrict__ kn_b2,
    unsigned* __restrict__ wsmax, float* __restrict__ pmax,
    float* __restrict__ par, int sb) {
    __shared__ float s_emb[E_];
    __shared__ float s_part[256];
    __shared__ float s_h[H_];
    __shared__ float s_sc[H_], s_sh[H_];
    __shared__ float s_mx[4];
    const int t = threadIdx.x;
    const int bn = blockIdx.x;

    s_emb[t] = emb[bn * E_ + t];

    // distance max: 2 points per thread
    float mu0 = mu[2 * bn], mu1 = mu[2 * bn + 1];
    float2 z0 = ((const float2*)z)[t];
    float2 z1 = ((const float2*)z)[t + 256];
    float d0 = z0.x - mu0, d1 = z0.y - mu1;
    float mx = fmaf(d0, d0, d1 * d1);
    d0 = z1.x - mu0; d1 = z1.y - mu1;
    mx = fmaxf(mx, fmaf(d0, d0, d1 * d1));
    #pragma unroll
    for (int off = 32; off; off >>= 1) mx = fmaxf(mx, __shfl_xor(mx, off, 64));
    if ((t & 63) == 0) s_mx[t >> 6] = mx;
    __syncthreads();
    if (t == 0) {
        float m4 = fmaxf(fmaxf(s_mx[0], s_mx[1]), fmaxf(s_mx[2], s_mx[3]));
        if (pmax) pmax[bn] = m4;
        else atomicMax(wsmax, __float_as_uint(m4));
    }

    // w1 partial dots: thread (h = t&63, q = t>>6) does 64 MACs
    {
        int h = t & 63, q = t >> 6;
        const f32x2* wr = (const f32x2*)(fg_w1 + h * E_ + q * 64);
        const f32x2* er = (const f32x2*)(s_emb + q * 64);
        f32x2 a2; a2.x = 0.f; a2.y = 0.f;
        #pragma unroll
        for (int e = 0; e < 32; e++) a2 = pfma(wr[e], er[e], a2);
        s_part[t] = a2.x + a2.y;
    }
    __syncthreads();
    if (t < H_) {
        float hv = s_part[t] + s_part[64 + t] + s_part[128 + t] + s_part[192 + t] + fg_b1[t];
        s_h[t] = gelu_e(hv);
    }
    __syncthreads();
    // w2: g = t>>1 (0..127), hf = t&1 — 32 MACs each, pair-combine via shfl
    {
        int g = t >> 1, hf = t & 1;
        const f32x2* wr = (const f32x2*)(fg_w2 + g * H_ + hf * 32);
        const f32x2* hr = (const f32x2*)(s_h + hf * 32);
        f32x2 a2; a2.x = 0.f; a2.y = 0.f;
        #pragma unroll
        for (int q2 = 0; q2 < 16; q2++) a2 = pfma(wr[q2], hr[q2], a2);
        float acc = a2.x + a2.y;
        acc += __shfl_xor(acc, 1, 64);
        if (!hf) {
            float val = acc + fg_b2[g];
            if (g < H_) s_sc[g] = val; else s_sh[g - H_] = val;
        }
    }
    __syncthreads();
    if (t < H_) {
        float sc = s_sc[t], sh = s_sh[t];
        float* p0 = par + bn * sb;
        p0[t]          = sc * kn_w0[t];            // A1
        p0[H_ + t]     = fmaf(sc, kn_b0[t], sh);   // A0
        p0[2 * H_ + t] = fmaf(sc, kn_b2[t], sh);   // T (MFMA C-init)
        p0[3 * H_ + t] = sc;                       // S (frag fold)
    }
}

// grid = 1024: ONE bn per block, 512 threads (8 waves), wave w: 4 tiles of
// 16 points. OCCUPANCY PLAY: all per-bn params (A1/A0/T/w4) stay in LDS
// broadcast (each proven neutral vs registers in r13-r18), per-tile z load,
// minimal ~45-50 VGPR transient live set + __launch_bounds__(512, 8)
// -> 64-VGPR cap -> 4 blocks/CU = 32 waves/CU: whole grid co-resident in
// ONE generation with 8 waves/SIMD to hide the chain-head latency.
__global__ __launch_bounds__(512, 8) void film_main_kernel(
    const float* __restrict__ z, const float* __restrict__ mu,
    const float* __restrict__ kn_w2, const float* __restrict__ kn_w4,
    const float* __restrict__ kn_b4,
    const unsigned* __restrict__ wsmax, const float* __restrict__ pmax,
    const float* __restrict__ par, int sb,
    float* __restrict__ out) {
    // s_p: A1[0:64) A0[64:128) T[128:192) w4[192:256)
    __shared__ __align__(16) float s_p[4 * H_];
    __shared__ bf16x8 s_bfr[8][64];   // [c*4+ct][lane]
    __shared__ float s_mx[4];
    const int t = threadIdx.x;
    const int bn = blockIdx.x;
    const int lane = t & 63, wid = t >> 6;      // wid 0..7
    const int kg = lane >> 4, cl = lane & 15;
    const int mbase = wid * 64;

    const float* pb = par + bn * sb;

    if (t < 192) s_p[t] = pb[t];
    else if (t < 256) s_p[t] = kn_w4[t - 192];

    // global max: waves 0-3 reduce the 1024 per-bn maxima (4 floats/thread)
    if (pmax) {
        if (t < 256) {
            f32x4 pv = ((const f32x4*)pmax)[t];
            float mym = fmaxf(fmaxf(pv[0], pv[1]), fmaxf(pv[2], pv[3]));
            #pragma unroll
            for (int off = 32; off; off >>= 1) mym = fmaxf(mym, __shfl_xor(mym, off, 64));
            if (lane == 0) s_mx[wid] = mym;
        }
    }

    // cooperative S-folded frag build: wave wid builds (c = wid>>2, ct = wid&3)
    {
        int c = wid >> 2, ct = wid & 3;
        float Sg = pb[192 + ct * 16 + cl];
        const float* wr = kn_w2 + (ct * 16 + cl) * H_ + c * 32 + kg * 8;
        f32x4 w0v = *(const f32x4*)(wr);
        f32x4 w1v = *(const f32x4*)(wr + 4);
        bf16x8 v;
        #pragma unroll
        for (int i = 0; i < 4; i++) {
            v[i]     = sbf(w0v[i] * Sg);
            v[4 + i] = sbf(w1v[i] * Sg);
        }
        s_bfr[wid][lane] = v;
    }

    float mu0 = mu[bn * 2], mu1 = mu[bn * 2 + 1];
    float b4v = kn_b4[0];

    __syncthreads();
    float maxd2 = pmax
        ? fmaxf(fmaxf(s_mx[0], s_mx[1]), fmaxf(s_mx[2], s_mx[3]))
        : __uint_as_float(*wsmax);
    float invd = __builtin_amdgcn_rcpf(__builtin_amdgcn_sqrtf(maxd2) + 1e-8f);
    const f32x4* p4 = (const f32x4*)s_p;
    float* outr = out + bn * M_ + mbase;

    #pragma unroll 2
    for (int tl = 0; tl < 4; ++tl) {
        float2 zt = ((const float2*)z)[mbase + tl * 16 + cl];
        float dz0 = zt.x - mu0, dz1 = zt.y - mu1;
        float nd = __builtin_amdgcn_sqrtf(fmaf(dz0, dz0, dz1 * dz1)) * invd;
        f32x2 ndv; ndv.x = nd; ndv.y = nd;

        // B-operand: x0[slot h = c*32+kg*8+j][col = point cl]
        bf16x8 xf[2];
        #pragma unroll
        for (int c = 0; c < 2; c++) {
            int qb = (c * 32 + kg * 8) >> 2;
            f32x4 a1a = p4[qb], a1b = p4[qb + 1];
            f32x4 a0a = p4[16 + qb], a0b = p4[16 + qb + 1];
            bf16x8 v;
            #pragma unroll
            for (int i = 0; i < 2; i++) {
                f32x2 x1; x1.x = a1a[2 * i]; x1.y = a1a[2 * i + 1];
                f32x2 x0; x0.x = a0a[2 * i]; x0.y = a0a[2 * i + 1];
                f32x2 g = gelu2(pfma(ndv, x1, x0));
                v[2 * i] = sbf(g.x); v[2 * i + 1] = sbf(g.y);
                f32x2 y1; y1.x = a1b[2 * i]; y1.y = a1b[2 * i + 1];
                f32x2 y0; y0.x = a0b[2 * i]; y0.y = a0b[2 * i + 1];
                f32x2 h = gelu2(pfma(ndv, y1, y0));
                v[4 + 2 * i] = sbf(h.x); v[5 + 2 * i] = sbf(h.y);
            }
            xf[c] = v;
        }

        // sequential per-ct: MFMA pair (C-init = T from LDS) + epilogue gelu
        f32x2 y2; y2.x = 0.f; y2.y = 0.f;
        #pragma unroll
        for (int ct = 0; ct < 4; ct++) {
            f32x4 a = p4[32 + ct * 4 + kg];
            a = __builtin_amdgcn_mfma_f32_16x16x32_bf16(s_bfr[ct][lane], xf[0], a, 0, 0, 0);
            a = __builtin_amdgcn_mfma_f32_16x16x32_bf16(s_bfr[4 + ct][lane], xf[1], a, 0, 0, 0);
            f32x4 wv = p4[48 + ct * 4 + kg];
            f32x2 a01; a01.x = a[0]; a01.y = a[1];
            f32x2 a23; a23.x = a[2]; a23.y = a[3];
            f32x2 w01; w01.x = wv[0]; w01.y = wv[1];
            f32x2 w23; w23.x = wv[2]; w23.y = wv[3];
            y2 = pfma(gelu2(a01), w01, y2);
            y2 = pfma(gelu2(a23), w23, y2);
        }
        float y = y2.x + y2.y;
        y += __shfl_xor(y, 16, 64);
        y += __shfl_xor(y, 32, 64);

        // quarter-wave kg==tl does a contiguous 16-float store
        if (kg == tl) {
            float E = __builtin_amdgcn_exp2f((y + b4v) * -1.44269504f);
            outr[tl * 16 + cl] = __builtin_amdgcn_rcpf(1.0f + E);
        }
    }
}

extern "C" void kernel_launch(void* const* d_in, const int* in_sizes, int n_in,
                              void* d_out, int out_size, void* d_ws, size_t ws_size,
                              hipStream_t stream) {
    const float* z      = (const float*)d_in[0];
    const float* mu     = (const float*)d_in[1];
    const float* emb    = (const float*)d_in[2];
    const float* fg_w1  = (const float*)d_in[3];
    const float* fg_b1  = (const float*)d_in[4];
    const float* fg_w2  = (const float*)d_in[5];
    const float* fg_b2  = (const float*)d_in[6];
    const float* kn_w0  = (const float*)d_in[7];
    const float* kn_b0  = (const float*)d_in[8];
    const float* kn_w2  = (const float*)d_in[9];
    const float* kn_b2  = (const float*)d_in[10];
    const float* kn_w4  = (const float*)d_in[11];
    const float* kn_b4  = (const float*)d_in[12];
    float* out = (float*)d_out;

    // primary: pmax[1024] at ws+0, par at ws+16KB -> 2 dispatches, no memset
    const size_t need = 16384 + (size_t)(B_ * N_) * 256 * sizeof(float);
    if (ws_size >= need) {
        float* pmax = (float*)d_ws;
        float* par  = (float*)((char*)d_ws + 16384);
        film_params_kernel<<<B_ * N_, 256, 0, stream>>>(
            z, mu, emb, fg_w1, fg_b1, fg_w2, fg_b2, kn_w0, kn_b0, kn_b2,
            nullptr, pmax, par, 256);
        film_main_kernel<<<B_ * N_, 512, 0, stream>>>(
            z, mu, kn_w2, kn_w4, kn_b4, nullptr, pmax, par, 256, out);
    } else {
        // legacy fallback: atomic max in ws, params staged in out (block bn
        // reads its own 512-float region before overwriting; all pb reads
        // precede the barrier, all stores follow it)
        unsigned* wsmax = (unsigned*)d_ws;
        float* par = out;
        hipMemsetAsync(d_ws, 0, 4, stream);
        film_params_kernel<<<B_ * N_, 256, 0, stream>>>(
            z, mu, emb, fg_w1, fg_b1, fg_w2, fg_b2, kn_w0, kn_b0, kn_b2,
            wsmax, nullptr, par, 512);
        film_main_kernel<<<B_ * N_, 512, 0, stream>>>(
            z, mu, kn_w2, kn_w4, kn_b4, wsmax, nullptr, par, 512, out);
    }
}

// Round 20
// 39.254 us; speedup vs baseline: 3.2494x; 3.2494x over previous
//
#include <hip/hip_runtime.h>
#include <hip/hip_bf16.h>
#include <math.h>

#define B_ 4
#define N_ 256
#define M_ 512
#define E_ 256
#define H_ 64

typedef __attribute__((ext_vector_type(8))) short bf16x8;
typedef __attribute__((ext_vector_type(4))) float f32x4;
typedef __attribute__((ext_vector_type(2))) float f32x2;

__device__ __forceinline__ f32x2 pfma(f32x2 a, f32x2 b, f32x2 c) {
    return __builtin_elementwise_fma(a, b, c);
}

// packed-pair tanh-form gelu with raw v_exp_f32:
// gelu(x) = x * rcp(1 + exp2(-k1*x - k2*x^3)); saturates correctly, NaN-free.
__device__ __forceinline__ f32x2 gelu2(f32x2 x) {
    f32x2 t = x * x;
    f32x2 k2; k2.x = -0.10294377f; k2.y = -0.10294377f;
    f32x2 k1; k1.x = -2.3022081f;  k1.y = -2.3022081f;
    f32x2 u = pfma(t, k2, k1);
    f32x2 un = x * u;
    f32x2 E;
    E.x = __builtin_amdgcn_exp2f(un.x);
    E.y = __builtin_amdgcn_exp2f(un.y);
    f32x2 one; one.x = 1.0f; one.y = 1.0f;
    f32x2 d = E + one;
    f32x2 r; r.x = __builtin_amdgcn_rcpf(d.x); r.y = __builtin_amdgcn_rcpf(d.y);
    return x * r;
}

// exact (erf) gelu for the FiLM generator path (params kernel only)
__device__ __forceinline__ float gelu_e(float x) {
    return 0.5f * x * (1.0f + erff(x * 0.70710678118654752f));
}

// fp32 -> bf16 bits via native convert (RNE)
__device__ __forceinline__ short sbf(float f) {
    __bf16 h = (__bf16)f;
    return __builtin_bit_cast(short, h);
}

// Per-(b,n): FiLM params + per-bn distance max. 256 threads.
// par[bn*sb] = { A1[64], A0[64], T[64], S[64] }
__global__ __launch_bounds__(256) void film_params_kernel(
    const float* __restrict__ z, const float* __restrict__ mu,
    const float* __restrict__ emb,
    const float* __restrict__ fg_w1, const float* __restrict__ fg_b1,
    const float* __restrict__ fg_w2, const float* __restrict__ fg_b2,
    const float* __restrict__ kn_w0, const float* __restrict__ kn_b0,
    const float* __restrict__ kn_b2,
    unsigned* __restrict__ wsmax, float* __restrict__ pmax,
    float* __restrict__ par, int sb) {
    __shared__ float s_emb[E_];
    __shared__ float s_part[256];
    __shared__ float s_h[H_];
    __shared__ float s_sc[H_], s_sh[H_];
    __shared__ float s_mx[4];
    const int t = threadIdx.x;
    const int bn = blockIdx.x;

    s_emb[t] = emb[bn * E_ + t];

    // distance max: 2 points per thread
    float mu0 = mu[2 * bn], mu1 = mu[2 * bn + 1];
    float2 z0 = ((const float2*)z)[t];
    float2 z1 = ((const float2*)z)[t + 256];
    float d0 = z0.x - mu0, d1 = z0.y - mu1;
    float mx = fmaf(d0, d0, d1 * d1);
    d0 = z1.x - mu0; d1 = z1.y - mu1;
    mx = fmaxf(mx, fmaf(d0, d0, d1 * d1));
    #pragma unroll
    for (int off = 32; off; off >>= 1) mx = fmaxf(mx, __shfl_xor(mx, off, 64));
    if ((t & 63) == 0) s_mx[t >> 6] = mx;
    __syncthreads();
    if (t == 0) {
        float m4 = fmaxf(fmaxf(s_mx[0], s_mx[1]), fmaxf(s_mx[2], s_mx[3]));
        if (pmax) pmax[bn] = m4;
        else atomicMax(wsmax, __float_as_uint(m4));
    }

    // w1 partial dots: thread (h = t&63, q = t>>6) does 64 MACs
    {
        int h = t & 63, q = t >> 6;
        const f32x2* wr = (const f32x2*)(fg_w1 + h * E_ + q * 64);
        const f32x2* er = (const f32x2*)(s_emb + q * 64);
        f32x2 a2; a2.x = 0.f; a2.y = 0.f;
        #pragma unroll
        for (int e = 0; e < 32; e++) a2 = pfma(wr[e], er[e], a2);
        s_part[t] = a2.x + a2.y;
    }
    __syncthreads();
    if (t < H_) {
        float hv = s_part[t] + s_part[64 + t] + s_part[128 + t] + s_part[192 + t] + fg_b1[t];
        s_h[t] = gelu_e(hv);
    }
    __syncthreads();
    // w2: g = t>>1 (0..127), hf = t&1 — 32 MACs each, pair-combine via shfl
    {
        int g = t >> 1, hf = t & 1;
        const f32x2* wr = (const f32x2*)(fg_w2 + g * H_ + hf * 32);
        const f32x2* hr = (const f32x2*)(s_h + hf * 32);
        f32x2 a2; a2.x = 0.f; a2.y = 0.f;
        #pragma unroll
        for (int q2 = 0; q2 < 16; q2++) a2 = pfma(wr[q2], hr[q2], a2);
        float acc = a2.x + a2.y;
        acc += __shfl_xor(acc, 1, 64);
        if (!hf) {
            float val = acc + fg_b2[g];
            if (g < H_) s_sc[g] = val; else s_sh[g - H_] = val;
        }
    }
    __syncthreads();
    if (t < H_) {
        float sc = s_sc[t], sh = s_sh[t];
        float* p0 = par + bn * sb;
        p0[t]          = sc * kn_w0[t];            // A1
        p0[H_ + t]     = fmaf(sc, kn_b0[t], sh);   // A0
        p0[2 * H_ + t] = fmaf(sc, kn_b2[t], sh);   // T (MFMA C-init)
        p0[3 * H_ + t] = sc;                       // S (frag fold)
    }
}

// grid = 1024: ONE bn per block, 512 threads (8 waves), wave w: 4 tiles of
// 16 points. NEW: the w4-dot epilogue runs as a SECOND MFMA. Row
// permutation pi(ct,r) = (ct&1)*32 + (r>>2)*8 + (ct>>1)*4 + (r&3) makes
// the first MFMA's C-layout coincide with the second MFMA's B-layout:
// zero cross-lane shuffles. w2/S/T loads use pi; w4 is replicated across
// all 16 A-rows; b4 rides in as C-init. Kills 16 pfma + 16 movs + 2
// dependent DS-shfls per tile off the critical path.
__global__ __launch_bounds__(512, 4) void film_main_kernel(
    const float* __restrict__ z, const float* __restrict__ mu,
    const float* __restrict__ kn_w2, const float* __restrict__ kn_w4,
    const float* __restrict__ kn_b4,
    const unsigned* __restrict__ wsmax, const float* __restrict__ pmax,
    const float* __restrict__ par, int sb,
    float* __restrict__ out) {
    __shared__ bf16x8 s_bfr[8][64];   // [c*4+ct][lane]
    __shared__ float s_mx[4];
    const int t = threadIdx.x;
    const int bn = blockIdx.x;
    const int lane = t & 63, wid = t >> 6;      // wid 0..7
    const int kg = lane >> 4, cl = lane & 15;
    const int mbase = wid * 64;

    const float* pb = par + bn * sb;

    // z prefetch for all 4 tiles (full unroll -> static indices)
    float2 zz[4];
    #pragma unroll
    for (int tl = 0; tl < 4; tl++) zz[tl] = ((const float2*)z)[mbase + tl * 16 + cl];

    // A-side params in registers: h = c*32 + kg*8 + q*4 + i
    f32x4 A1v[2][2], A0v[2][2];
    #pragma unroll
    for (int c = 0; c < 2; c++)
        #pragma unroll
        for (int q = 0; q < 2; q++) {
            A1v[c][q] = *(const f32x4*)(pb + c * 32 + kg * 8 + q * 4);
            A0v[c][q] = *(const f32x4*)(pb + 64 + c * 32 + kg * 8 + q * 4);
        }

    // T in registers, PERMUTED: Tr[ct][i] = T[pi(ct, kg*4+i)]
    //   pi(ct, kg*4+i) = (ct&1)*32 + kg*8 + (ct>>1)*4 + i  (i-contiguous)
    f32x4 Tr[4];
    #pragma unroll
    for (int ct = 0; ct < 4; ct++)
        Tr[ct] = *(const f32x4*)(pb + 128 + (ct & 1) * 32 + kg * 8 + (ct >> 1) * 4);

    // w4 as second-MFMA A-fragments (all rows identical): wf[c][j] =
    // w4[c*32 + kg*8 + j], bf16
    bf16x8 wf[2];
    #pragma unroll
    for (int c = 0; c < 2; c++) {
        f32x4 wa = *(const f32x4*)(kn_w4 + c * 32 + kg * 8);
        f32x4 wb = *(const f32x4*)(kn_w4 + c * 32 + kg * 8 + 4);
        bf16x8 v;
        #pragma unroll
        for (int i = 0; i < 4; i++) { v[i] = sbf(wa[i]); v[4 + i] = sbf(wb[i]); }
        wf[c] = v;
    }

    // global max: waves 0-3 reduce the 1024 per-bn maxima
    if (pmax) {
        if (t < 256) {
            f32x4 pv = ((const f32x4*)pmax)[t];
            float mym = fmaxf(fmaxf(pv[0], pv[1]), fmaxf(pv[2], pv[3]));
            #pragma unroll
            for (int off = 32; off; off >>= 1) mym = fmaxf(mym, __shfl_xor(mym, off, 64));
            if (lane == 0) s_mx[wid] = mym;
        }
    }

    // cooperative S-folded frag build: wave wid builds (c = wid>>2, ct = wid&3)
    // MFMA-ct row r (= cl) holds w2 row pi(ct, r), scaled by S[pi(ct, r)]
    {
        int c = wid >> 2, ct = wid & 3;
        int row_g = (ct & 1) * 32 + (cl >> 2) * 8 + (ct >> 1) * 4 + (cl & 3);
        float Sg = pb[192 + row_g];
        const float* wr = kn_w2 + row_g * H_ + c * 32 + kg * 8;
        f32x4 w0v = *(const f32x4*)(wr);
        f32x4 w1v = *(const f32x4*)(wr + 4);
        bf16x8 v;
        #pragma unroll
        for (int i = 0; i < 4; i++) {
            v[i]     = sbf(w0v[i] * Sg);
            v[4 + i] = sbf(w1v[i] * Sg);
        }
        s_bfr[c * 4 + ct][lane] = v;
    }

    float mu0 = mu[bn * 2], mu1 = mu[bn * 2 + 1];
    float b4v = kn_b4[0];

    __syncthreads();
    float maxd2 = pmax
        ? fmaxf(fmaxf(s_mx[0], s_mx[1]), fmaxf(s_mx[2], s_mx[3]))
        : __uint_as_float(*wsmax);
    float invd = __builtin_amdgcn_rcpf(__builtin_amdgcn_sqrtf(maxd2) + 1e-8f);
    float* outr = out + bn * M_ + mbase;

    #pragma unroll
    for (int tl = 0; tl < 4; ++tl) {
        float dz0 = zz[tl].x - mu0, dz1 = zz[tl].y - mu1;
        float nd = __builtin_amdgcn_sqrtf(fmaf(dz0, dz0, dz1 * dz1)) * invd;
        f32x2 ndv; ndv.x = nd; ndv.y = nd;

        // B-operand: x0[slot h = c*32+kg*8+j][col = point cl], A from regs
        bf16x8 xf[2];
        #pragma unroll
        for (int c = 0; c < 2; c++) {
            bf16x8 v;
            #pragma unroll
            for (int q = 0; q < 2; q++) {
                f32x2 x1a; x1a.x = A1v[c][q][0]; x1a.y = A1v[c][q][1];
                f32x2 x1b; x1b.x = A1v[c][q][2]; x1b.y = A1v[c][q][3];
                f32x2 x0a; x0a.x = A0v[c][q][0]; x0a.y = A0v[c][q][1];
                f32x2 x0b; x0b.x = A0v[c][q][2]; x0b.y = A0v[c][q][3];
                f32x2 g1 = gelu2(pfma(ndv, x1a, x0a));
                f32x2 g2 = gelu2(pfma(ndv, x1b, x0b));
                v[q * 4]     = sbf(g1.x); v[q * 4 + 1] = sbf(g1.y);
                v[q * 4 + 2] = sbf(g2.x); v[q * 4 + 3] = sbf(g2.y);
            }
            xf[c] = v;
        }

        // first MFMA pass: D[pi(ct, kg*4+i)][cl] with C-init = T, then gelu
        f32x4 g4[4];
        #pragma unroll
        for (int ct = 0; ct < 4; ct++) {
            f32x4 a = Tr[ct];
            a = __builtin_amdgcn_mfma_f32_16x16x32_bf16(s_bfr[ct][lane], xf[0], a, 0, 0, 0);
            a = __builtin_amdgcn_mfma_f32_16x16x32_bf16(s_bfr[4 + ct][lane], xf[1], a, 0, 0, 0);
            f32x2 a01; a01.x = a[0]; a01.y = a[1];
            f32x2 a23; a23.x = a[2]; a23.y = a[3];
            f32x2 g01 = gelu2(a01), g23 = gelu2(a23);
            g4[ct][0] = g01.x; g4[ct][1] = g01.y; g4[ct][2] = g23.x; g4[ct][3] = g23.y;
        }

        // P as second-MFMA B-fragments (layouts coincide by pi):
        // pf[0] = {g4[0], g4[2]} covers k = kg*8 + 0..7 (c=0)
        // pf[1] = {g4[1], g4[3]} covers k = 32 + kg*8 + 0..7 (c=1)
        bf16x8 pf0, pf1;
        #pragma unroll
        for (int i = 0; i < 4; i++) {
            pf0[i]     = sbf(g4[0][i]);
            pf0[4 + i] = sbf(g4[2][i]);
            pf1[i]     = sbf(g4[1][i]);
            pf1[4 + i] = sbf(g4[3][i]);
        }

        // second MFMA: y[cl] = sum_g P[g][cl] * w4[g] + b4 (C-init)
        f32x4 yb; yb[0] = b4v; yb[1] = b4v; yb[2] = b4v; yb[3] = b4v;
        yb = __builtin_amdgcn_mfma_f32_16x16x32_bf16(wf[0], pf0, yb, 0, 0, 0);
        yb = __builtin_amdgcn_mfma_f32_16x16x32_bf16(wf[1], pf1, yb, 0, 0, 0);

        // every lane now holds y for point cl; quarter-wave kg==tl stores
        if (kg == tl) {
            float E = __builtin_amdgcn_exp2f(yb[0] * -1.44269504f);
            outr[tl * 16 + cl] = __builtin_amdgcn_rcpf(1.0f + E);
        }
    }
}

extern "C" void kernel_launch(void* const* d_in, const int* in_sizes, int n_in,
                              void* d_out, int out_size, void* d_ws, size_t ws_size,
                              hipStream_t stream) {
    const float* z      = (const float*)d_in[0];
    const float* mu     = (const float*)d_in[1];
    const float* emb    = (const float*)d_in[2];
    const float* fg_w1  = (const float*)d_in[3];
    const float* fg_b1  = (const float*)d_in[4];
    const float* fg_w2  = (const float*)d_in[5];
    const float* fg_b2  = (const float*)d_in[6];
    const float* kn_w0  = (const float*)d_in[7];
    const float* kn_b0  = (const float*)d_in[8];
    const float* kn_w2  = (const float*)d_in[9];
    const float* kn_b2  = (const float*)d_in[10];
    const float* kn_w4  = (const float*)d_in[11];
    const float* kn_b4  = (const float*)d_in[12];
    float* out = (float*)d_out;

    // primary: pmax[1024] at ws+0, par at ws+16KB -> 2 dispatches, no memset
    const size_t need = 16384 + (size_t)(B_ * N_) * 256 * sizeof(float);
    if (ws_size >= need) {
        float* pmax = (float*)d_ws;
        float* par  = (float*)((char*)d_ws + 16384);
        film_params_kernel<<<B_ * N_, 256, 0, stream>>>(
            z, mu, emb, fg_w1, fg_b1, fg_w2, fg_b2, kn_w0, kn_b0, kn_b2,
            nullptr, pmax, par, 256);
        film_main_kernel<<<B_ * N_, 512, 0, stream>>>(
            z, mu, kn_w2, kn_w4, kn_b4, nullptr, pmax, par, 256, out);
    } else {
        // legacy fallback: atomic max in ws, params staged in out (block bn
        // reads its own 512-float region before overwriting; all pb reads
        // precede the barrier, all stores follow it)
        unsigned* wsmax = (unsigned*)d_ws;
        float* par = out;
        hipMemsetAsync(d_ws, 0, 4, stream);
        film_params_kernel<<<B_ * N_, 256, 0, stream>>>(
            z, mu, emb, fg_w1, fg_b1, fg_w2, fg_b2, kn_w0, kn_b0, kn_b2,
            wsmax, nullptr, par, 512);
        film_main_kernel<<<B_ * N_, 512, 0, stream>>>(
            z, mu, kn_w2, kn_w4, kn_b4, wsmax, nullptr, par, 512, out);
    }
}